// Round 5
// baseline (146.811 us; speedup 1.0000x reference)
//
#include <hip/hip_runtime.h>
#include <math.h>

// Hash-grid (instant-NGP style) trilinear interpolation, layer 8.
// T = 2^19 entries x F=2 floats; N = 2^21 points x 3 dims.
// Hash: (ix ^ iy*2654435761 ^ iz*805459861) mod 2^19 -- uint32 math is
// bit-exact with the reference's int64 (power-of-two modulus).
//
// Round-3: throughput-bound on gathers (4x MLP batching = no change).
// Theory: L1 line-fill amplification -- each random 8B gather misses L1
// and fills a 128B line from L2: 16.7M x 128B = 2.1GB at 34.5TB/s = 62us
// ~= observed 65us. Round-4's sc0 inline asm crashed at runtime;
// this round uses __builtin_nontemporal_load (nt = no L1 allocate) on the
// table gathers instead -- supported builtin, same L1-bypass intent.

#define HT_MASK  524287u
#define PRIME_Y  2654435761u
#define PRIME_Z  805459861u
#define N_POINTS 2097152
#define PPT      4

typedef float vfloat4 __attribute__((ext_vector_type(4)));
typedef float vfloat2 __attribute__((ext_vector_type(2)));

__global__ __launch_bounds__(256) void hashgrid_interp_kernel(
    const vfloat4* __restrict__ X4,    // N*3 floats viewed as float4
    const vfloat2* __restrict__ tb,    // T x float2
    vfloat4* __restrict__ out4,        // N x float2 viewed as float4
    float scale)
{
    int t = blockIdx.x * blockDim.x + threadIdx.x;   // 0 .. N/4-1

    // Points [4t, 4t+4): 12 floats = 3 aligned float4 loads (nontemporal:
    // X is streamed once; don't evict the table from L2).
    vfloat4 q0 = __builtin_nontemporal_load(&X4[3 * t + 0]);
    vfloat4 q1 = __builtin_nontemporal_load(&X4[3 * t + 1]);
    vfloat4 q2 = __builtin_nontemporal_load(&X4[3 * t + 2]);

    float px[PPT] = {q0.x, q0.w, q1.z, q2.y};
    float py[PPT] = {q0.y, q1.x, q1.w, q2.z};
    float pz[PPT] = {q0.z, q1.y, q2.x, q2.w};

    unsigned idx[PPT][8];
    float wx[PPT], wy[PPT], wz[PPT];

    #pragma unroll
    for (int p = 0; p < PPT; ++p) {
        float xs = px[p] * scale;
        float ys = py[p] * scale;
        float zs = pz[p] * scale;

        float fx = floorf(xs), fy = floorf(ys), fz = floorf(zs);
        wx[p] = xs - fx;  wy[p] = ys - fy;  wz[p] = zs - fz;

        unsigned hx0 = (unsigned)(int)fx;
        unsigned hy0 = (unsigned)(int)fy * PRIME_Y;
        unsigned hz0 = (unsigned)(int)fz * PRIME_Z;
        unsigned hx1 = (unsigned)(int)ceilf(xs);
        unsigned hy1 = (unsigned)(int)ceilf(ys) * PRIME_Y;
        unsigned hz1 = (unsigned)(int)ceilf(zs) * PRIME_Z;

        // corner c = (bx<<2)|(by<<1)|bz
        idx[p][0] = (hx0 ^ hy0 ^ hz0) & HT_MASK;
        idx[p][1] = (hx0 ^ hy0 ^ hz1) & HT_MASK;
        idx[p][2] = (hx0 ^ hy1 ^ hz0) & HT_MASK;
        idx[p][3] = (hx0 ^ hy1 ^ hz1) & HT_MASK;
        idx[p][4] = (hx1 ^ hy0 ^ hz0) & HT_MASK;
        idx[p][5] = (hx1 ^ hy0 ^ hz1) & HT_MASK;
        idx[p][6] = (hx1 ^ hy1 ^ hz0) & HT_MASK;
        idx[p][7] = (hx1 ^ hy1 ^ hz1) & HT_MASK;
    }

    // Issue all 32 gathers (nt: no L1 allocate -> no 128B line-fill
    // amplification) before consuming any.
    vfloat2 v[PPT][8];
    #pragma unroll
    for (int p = 0; p < PPT; ++p) {
        #pragma unroll
        for (int c = 0; c < 8; ++c) {
            v[p][c] = __builtin_nontemporal_load(&tb[idx[p][c]]);
        }
    }

    float2 r[PPT];
    #pragma unroll
    for (int p = 0; p < PPT; ++p) {
        float omx = 1.0f - wx[p], omy = 1.0f - wy[p], omz = 1.0f - wz[p];

        float p00x = v[p][0].x * omx + v[p][4].x * wx[p];
        float p00y = v[p][0].y * omx + v[p][4].y * wx[p];
        float p01x = v[p][1].x * omx + v[p][5].x * wx[p];
        float p01y = v[p][1].y * omx + v[p][5].y * wx[p];
        float p10x = v[p][2].x * omx + v[p][6].x * wx[p];
        float p10y = v[p][2].y * omx + v[p][6].y * wx[p];
        float p11x = v[p][3].x * omx + v[p][7].x * wx[p];
        float p11y = v[p][3].y * omx + v[p][7].y * wx[p];

        float p0x = p00x * omy + p10x * wy[p];
        float p0y = p00y * omy + p10y * wy[p];
        float p1x = p01x * omy + p11x * wy[p];
        float p1y = p01y * omy + p11y * wy[p];

        r[p].x = p0x * omz + p1x * wz[p];
        r[p].y = p0y * omz + p1y * wz[p];
    }

    vfloat4 o0 = {r[0].x, r[0].y, r[1].x, r[1].y};
    vfloat4 o1 = {r[2].x, r[2].y, r[3].x, r[3].y};
    __builtin_nontemporal_store(o0, &out4[2 * t + 0]);
    __builtin_nontemporal_store(o1, &out4[2 * t + 1]);
}

extern "C" void kernel_launch(void* const* d_in, const int* in_sizes, int n_in,
                              void* d_out, int out_size, void* d_ws, size_t ws_size,
                              hipStream_t stream) {
    const vfloat4* X4    = (const vfloat4*)d_in[0];
    const vfloat2* table = (const vfloat2*)d_in[1];
    vfloat4* out4 = (vfloat4*)d_out;

    // RES computed exactly as the reference does (double precision on host).
    double growth = exp((log(512.0) - log(16.0)) / 15.0);
    double res = pow(growth, 8.0) * 16.0;
    float scale = (float)(res - 1.0);

    int block = 256;
    int grid = N_POINTS / (block * PPT);  // 2048 blocks
    hashgrid_interp_kernel<<<grid, block, 0, stream>>>(X4, table, out4, scale);
}

// Round 6
// 61.770 us; speedup vs baseline: 2.3768x; 2.3768x over previous
//
#include <hip/hip_runtime.h>
#include <math.h>

// Hash-grid (instant-NGP style) trilinear interpolation, layer 8.
// T = 2^19 entries x F=2 floats; N = 2^21 points x 3 dims.
// Hash: (ix ^ iy*2654435761 ^ iz*805459861) mod 2^19 -- uint32 math is
// bit-exact with the reference's int64 (power-of-two modulus).
//
// Evidence so far:
//  r1: latency theory -> 32-deep gather batch: NO change  => throughput-bound.
//  r5: nt on gathers: FETCH 33->107MB, 2.2x slower => nt kills L2 residency;
//      table MUST stay normally cached. Limit = gather request rate
//      (~16.7M independent 8B requests, ~2cy/request at TA/L1).
// This round: XOR-1 pairing. x-prime is 1, so for even ix0 the two
// x-corners hash to {h, h^1} = one aligned float4 load. Odd-ix0 lanes do a
// predicated 8B load for the x1 corner. Avg requests/point: 8 -> 6.

#define HT_MASK  524287u
#define PRIME_Y  2654435761u
#define PRIME_Z  805459861u
#define N_POINTS 2097152
#define PPT      4

typedef float vfloat4 __attribute__((ext_vector_type(4)));
typedef float vfloat2 __attribute__((ext_vector_type(2)));

__global__ __launch_bounds__(256) void hashgrid_interp_kernel(
    const vfloat4* __restrict__ X4,    // N*3 floats viewed as float4
    const vfloat2* __restrict__ tb2,   // table as float2 entries
    const vfloat4* __restrict__ tb4,   // table as float4 entry-pairs
    vfloat4* __restrict__ out4,        // N x float2 viewed as float4
    float scale)
{
    int t = blockIdx.x * blockDim.x + threadIdx.x;   // 0 .. N/4-1

    // Points [4t, 4t+4): 12 floats = 3 aligned float4 loads (nontemporal:
    // X is streamed once; don't let it evict the table from L2).
    vfloat4 q0 = __builtin_nontemporal_load(&X4[3 * t + 0]);
    vfloat4 q1 = __builtin_nontemporal_load(&X4[3 * t + 1]);
    vfloat4 q2 = __builtin_nontemporal_load(&X4[3 * t + 2]);

    float px[PPT] = {q0.x, q0.w, q1.z, q2.y};
    float py[PPT] = {q0.y, q1.x, q1.w, q2.z};
    float pz[PPT] = {q0.z, q1.y, q2.x, q2.w};

    float2 r[PPT];

    #pragma unroll
    for (int p = 0; p < PPT; ++p) {
        float xs = px[p] * scale;
        float ys = py[p] * scale;
        float zs = pz[p] * scale;

        float fx = floorf(xs), fy = floorf(ys), fz = floorf(zs);
        float wx = xs - fx, wy = ys - fy, wz = zs - fz;

        unsigned hx0 = (unsigned)(int)fx;
        unsigned hx1 = (unsigned)(int)ceilf(xs);
        unsigned hy0 = (unsigned)(int)fy * PRIME_Y;
        unsigned hy1 = (unsigned)(int)ceilf(ys) * PRIME_Y;
        unsigned hz0 = (unsigned)(int)fz * PRIME_Z;
        unsigned hz1 = (unsigned)(int)ceilf(zs) * PRIME_Z;

        // c2 = (by<<1)|bz: [0]=y0z0, [1]=y0z1, [2]=y1z0, [3]=y1z1
        unsigned byz[4] = {hy0 ^ hz0, hy0 ^ hz1, hy1 ^ hz0, hy1 ^ hz1};
        bool oddx = (hx0 & 1u) != 0u;

        // Pair loads: table entries {h0 & ~1, h0 | 1} in one 16B load.
        // For even ix0, h4 = h0^1 is the other half -> both x-corners.
        unsigned h0[4], h4[4];
        vfloat4 pr[4];
        #pragma unroll
        for (int c = 0; c < 4; ++c) {
            h0[c] = (hx0 ^ byz[c]) & HT_MASK;
            h4[c] = (hx1 ^ byz[c]) & HT_MASK;
            pr[c] = tb4[h0[c] >> 1];
        }

        // Odd-ix0 lanes: x1 corner is NOT adjacent -> predicated 8B loads.
        vfloat2 vo[4] = {{0.f, 0.f}, {0.f, 0.f}, {0.f, 0.f}, {0.f, 0.f}};
        if (oddx) {
            #pragma unroll
            for (int c = 0; c < 4; ++c) vo[c] = tb2[h4[c]];
        }

        float v0x[4], v0y[4], v4x[4], v4y[4];
        #pragma unroll
        for (int c = 0; c < 4; ++c) {
            bool sel = (h0[c] & 1u) != 0u;           // h0's slot in the pair
            float lox = pr[c].x, loy = pr[c].y;
            float hix = pr[c].z, hiy = pr[c].w;
            v0x[c] = sel ? hix : lox;
            v0y[c] = sel ? hiy : loy;
            float ux = sel ? lox : hix;              // table[h0^1]
            float uy = sel ? loy : hiy;
            v4x[c] = oddx ? vo[c].x : ux;
            v4y[c] = oddx ? vo[c].y : uy;
            // integral xs: h4==h0, paired value wrong but wx==0 -> weight 0.
        }

        float omx = 1.0f - wx, omy = 1.0f - wy, omz = 1.0f - wz;

        float p00x = v0x[0] * omx + v4x[0] * wx;
        float p00y = v0y[0] * omx + v4y[0] * wx;
        float p01x = v0x[1] * omx + v4x[1] * wx;
        float p01y = v0y[1] * omx + v4y[1] * wx;
        float p10x = v0x[2] * omx + v4x[2] * wx;
        float p10y = v0y[2] * omx + v4y[2] * wx;
        float p11x = v0x[3] * omx + v4x[3] * wx;
        float p11y = v0y[3] * omx + v4y[3] * wx;

        float p0x = p00x * omy + p10x * wy;
        float p0y = p00y * omy + p10y * wy;
        float p1x = p01x * omy + p11x * wy;
        float p1y = p01y * omy + p11y * wy;

        r[p].x = p0x * omz + p1x * wz;
        r[p].y = p0y * omz + p1y * wz;
    }

    vfloat4 o0 = {r[0].x, r[0].y, r[1].x, r[1].y};
    vfloat4 o1 = {r[2].x, r[2].y, r[3].x, r[3].y};
    __builtin_nontemporal_store(o0, &out4[2 * t + 0]);
    __builtin_nontemporal_store(o1, &out4[2 * t + 1]);
}

extern "C" void kernel_launch(void* const* d_in, const int* in_sizes, int n_in,
                              void* d_out, int out_size, void* d_ws, size_t ws_size,
                              hipStream_t stream) {
    const vfloat4* X4    = (const vfloat4*)d_in[0];
    const vfloat2* tb2   = (const vfloat2*)d_in[1];
    const vfloat4* tb4   = (const vfloat4*)d_in[1];
    vfloat4* out4 = (vfloat4*)d_out;

    // RES computed exactly as the reference does (double precision on host).
    double growth = exp((log(512.0) - log(16.0)) / 15.0);
    double res = pow(growth, 8.0) * 16.0;
    float scale = (float)(res - 1.0);

    int block = 256;
    int grid = N_POINTS / (block * PPT);  // 2048 blocks
    hashgrid_interp_kernel<<<grid, block, 0, stream>>>(X4, tb2, tb4, out4, scale);
}